// Round 7
// baseline (153.009 us; speedup 1.0000x reference)
//
#include <hip/hip_runtime.h>
#include <math.h>

#define A_N 2048
#define NLAYERS 2057
#define NUNITS 4096               // 2 half-chunks (128 rows) per expert
#define NPART  4097               // part row 0 = middle, 1+j = unit j

// ws layout (float offsets)
#define PART_OFF  0               // 4097*256 = 1048832
#define PART2_OFF 1048832         // 64*256 = 16384
#define GSUM_OFF  (PART2_OFF + 16384)
#define WSUM_OFF  (GSUM_OFF + 1)
#define CTR_OFF   (GSUM_OFF + 4)  // int work-steal counter (4B, reset each launch)

typedef float f4 __attribute__((ext_vector_type(4)));

// ---- helpers (256-thread sections) ----

__device__ __forceinline__ void head256(const float* sx, float* r0, float* r1,
                                        const float* W2, const float* b2,
                                        float scale, float* dest, int t)
{
    float xv = sx[t];
    r0[t] = xv * W2[2*t];
    r1[t] = xv * W2[2*t+1];
    __syncthreads();
    for (int s = 128; s > 0; s >>= 1) {
        if (t < s) { r0[t] += r0[t+s]; r1[t] += r1[t+s]; }
        __syncthreads();
    }
    if (t == 0) {
        float o0 = r0[0] + b2[0], o1 = r1[0] + b2[1];
        float m  = fmaxf(o0, o1);
        float e0 = expf(o0 - m), e1 = expf(o1 - m);
        float inv = scale / (e0 + e1);
        dest[0] = e0 * inv;
        dest[1] = e1 * inv;
    }
    __syncthreads();
}

// sx = relu(sx @ W + b), register-light (block-0 chain only)
__device__ __forceinline__ void mv256(float* sx, const float* __restrict__ W,
                                      const float* __restrict__ b, int t)
{
    float acc = 0.f;
    #pragma unroll 16
    for (int k = 0; k < 256; ++k) acc += sx[k] * W[k*256 + t];
    acc = fmaxf(acc + b[t], 0.f);
    __syncthreads();
    sx[t] = acc;
    __syncthreads();
}

// pull nf4 float4s at base into L3 (loads kept live via asm consume)
__device__ __forceinline__ void warm64k(const float* base, int nf4, int t)
{
    const f4* p = (const f4*)base;
    for (int i = t; i < nf4; i += 256) {
        f4 v = p[i];
        asm volatile("" :: "v"(v.x), "v"(v.y), "v"(v.z), "v"(v.w));
    }
}

// ---- kernel 1: base/middle chain + work-stolen expert units (2048 blocks) ----
__global__ __launch_bounds__(256) void k_main(
    const float* __restrict__ X, const int* __restrict__ Xm,
    const float* __restrict__ bfv,
    const float* __restrict__ Wbf, const float* __restrict__ bbf,
    const float* __restrict__ Wbr, const float* __restrict__ bbr,
    const float* __restrict__ Wbo, const float* __restrict__ bbo,
    const float* __restrict__ Wm, const float* __restrict__ bm,
    const float* __restrict__ Wmo, const float* __restrict__ bmo,
    const float* __restrict__ Wa, const float* __restrict__ ba,
    const float* __restrict__ Wao, const float* __restrict__ bao,
    const float* __restrict__ Wef, const float* __restrict__ lw,
    const float* __restrict__ Wer, const float* __restrict__ Weo,
    const float* __restrict__ bef, const float* __restrict__ ber,
    float* __restrict__ out, float* __restrict__ ws)
{
    __shared__ float sg[256];
    __shared__ float sacc[4][256];
    __shared__ int sjs;
    int b = blockIdx.x, t = threadIdx.x;
    int quad = t >> 6, lane = t & 63;
    float* part = ws + PART_OFF;
    int* ctr = (int*)(ws + CTR_OFF);

    // ---- L3 warming (blocks 1..34) ----
    if (b >= 1 && b <= 34) {
        int wi = b - 1;
        if      (wi < 12) warm64k(Wbr + (size_t)wi * 16384, 4096, t);        // 768KB
        else if (wi < 16) warm64k(Wm + (size_t)(wi - 12) * 16384, 4096, t);  // 256KB
        else if (wi < 28) warm64k(Wer + (size_t)(wi - 16) * 16384, 4096, t); // 768KB
        else if (wi == 28) { warm64k(Weo, 512, t); warm64k(Wbo, 512, t); }
        else if (wi == 29) { warm64k(Wmo, 128, t); warm64k(bef, 64, t); warm64k(ber, 192, t); }
        else warm64k(Wef + (size_t)A_N * 65536 + (size_t)(wi - 30) * 16384, 4096, t);
    }

    if (b == 0) {
        // ---- mask-weighted sums ----
        float ga = 0.f;
        for (int a = t; a < A_N; a += 256) if (Xm[a] != 0) ga += lw[4 + a];
        sacc[0][t] = ga; __syncthreads();
        for (int s = 128; s > 0; s >>= 1) { if (t < s) sacc[0][t] += sacc[0][t+s]; __syncthreads(); }
        if (t == 0) {
            float gaux = sacc[0][0];
            ws[GSUM_OFF] = gaux + lw[2056];
            ws[WSUM_OFF] = lw[0]+lw[1]+lw[2]+lw[3] + gaux
                         + lw[2052]+lw[2053]+lw[2054]+lw[2055]+lw[2056];
        }
        __syncthreads();

        // ---- base stack + middle ----
        sg[t] = fmaxf(bfv[0] * Wbf[t] + bbf[t], 0.f);
        __syncthreads();
        head256(sg, sacc[0], sacc[1], Wbo, bbo, lw[0], out + 2, t);
        for (int i = 0; i < 3; ++i) {
            mv256(sg, Wbr + i*65536, bbr + i*256, t);
            head256(sg, sacc[0], sacc[1], Wbo + (i+1)*512, bbo + (i+1)*2,
                    lw[i+1], out + 2 + (i+1)*2, t);
        }
        mv256(sg, Wm, bm, t);
        head256(sg, sacc[0], sacc[1], Wmo, bmo, lw[2056], out + 2 + 2056*2, t);
        sg[t] *= lw[2056];
        __syncthreads();

        // ---- middle chunk: 256 rows of We_first (L3-warm) ----
        const f4* Wb4 = (const f4*)(Wef + (size_t)A_N * 65536) + (size_t)quad*64*64 + lane;
        const float* sgw = sg + quad*64;
        f4 acc = {0.f, 0.f, 0.f, 0.f};
        #pragma unroll
        for (int it = 0; it < 8; ++it) {
            f4 v0 = Wb4[(it*8+0)*64]; f4 v1 = Wb4[(it*8+1)*64];
            f4 v2 = Wb4[(it*8+2)*64]; f4 v3 = Wb4[(it*8+3)*64];
            f4 v4 = Wb4[(it*8+4)*64]; f4 v5 = Wb4[(it*8+5)*64];
            f4 v6 = Wb4[(it*8+6)*64]; f4 v7 = Wb4[(it*8+7)*64];
            float g0 = sgw[it*8+0], g1 = sgw[it*8+1], g2 = sgw[it*8+2], g3 = sgw[it*8+3];
            float g4 = sgw[it*8+4], g5 = sgw[it*8+5], g6 = sgw[it*8+6], g7 = sgw[it*8+7];
            acc += g0*v0 + g1*v1 + g2*v2 + g3*v3 + g4*v4 + g5*v5 + g6*v6 + g7*v7;
        }
        sacc[quad][lane*4+0] = acc.x; sacc[quad][lane*4+1] = acc.y;
        sacc[quad][lane*4+2] = acc.z; sacc[quad][lane*4+3] = acc.w;
        __syncthreads();
        part[t] = sacc[0][t] + sacc[1][t] + sacc[2][t] + sacc[3][t];
    }

    // ---- dynamic work-steal loop: unit j -> expert j>>1, half j&1 (128 rows) ----
    for (;;) {
        __syncthreads();                       // protect sjs/sg/sacc reuse
        if (t == 0) sjs = atomicAdd(ctr, 1);
        __syncthreads();
        int j = sjs;
        if (j >= NUNITS) break;
        int e = j >> 1, half = j & 1;
        if (Xm[e] == 0) {
            if (half == 0 && t == 0) { out[2 + (4+e)*2] = 0.f; out[2 + (4+e)*2 + 1] = 0.f; }
            continue;
        }
        float xv = X[e];
        float w  = lw[4 + e];
        if (half == 0) {
            // full h (head needs all 256) + aux softmax head
            float h = fmaxf(xv * Wa[e*256 + t] + ba[e*256 + t], 0.f);
            sg[t] = h * w;
            float2 wo = *(const float2*)&Wao[(size_t)e*512 + 2*t];
            sacc[0][t] = h * wo.x;
            sacc[1][t] = h * wo.y;
            __syncthreads();
            for (int s = 128; s > 0; s >>= 1) {
                if (t < s) { sacc[0][t] += sacc[0][t+s]; sacc[1][t] += sacc[1][t+s]; }
                __syncthreads();
            }
            if (t == 0) {
                float o0 = sacc[0][0] + bao[2*e], o1 = sacc[1][0] + bao[2*e+1];
                float m  = fmaxf(o0, o1);
                float e0 = expf(o0 - m), e1 = expf(o1 - m);
                float inv = w / (e0 + e1);     // * lw * mask; /wsum deferred
                out[2 + (4+e)*2]     = e0 * inv;
                out[2 + (4+e)*2 + 1] = e1 * inv;
            }
            __syncthreads();                   // sacc reused as matvec scratch below
        } else {
            if (t < 128) {
                int r = 128 + t;
                float h = fmaxf(xv * Wa[e*256 + r] + ba[e*256 + r], 0.f);
                sg[r] = h * w;
            }
            __syncthreads();
        }
        // 128-row matvec: wave quad owns rows rbase..rbase+32
        int rbase = half*128 + quad*32;
        const f4* Wb4 = (const f4*)(Wef + (size_t)e * 65536) + (size_t)rbase*64 + lane;
        const float* sgw = sg + rbase;
        f4 acc = {0.f, 0.f, 0.f, 0.f};
        #pragma unroll
        for (int it = 0; it < 4; ++it) {
            f4 v0 = __builtin_nontemporal_load(&Wb4[(it*8+0)*64]);
            f4 v1 = __builtin_nontemporal_load(&Wb4[(it*8+1)*64]);
            f4 v2 = __builtin_nontemporal_load(&Wb4[(it*8+2)*64]);
            f4 v3 = __builtin_nontemporal_load(&Wb4[(it*8+3)*64]);
            f4 v4 = __builtin_nontemporal_load(&Wb4[(it*8+4)*64]);
            f4 v5 = __builtin_nontemporal_load(&Wb4[(it*8+5)*64]);
            f4 v6 = __builtin_nontemporal_load(&Wb4[(it*8+6)*64]);
            f4 v7 = __builtin_nontemporal_load(&Wb4[(it*8+7)*64]);
            float g0 = sgw[it*8+0], g1 = sgw[it*8+1], g2 = sgw[it*8+2], g3 = sgw[it*8+3];
            float g4 = sgw[it*8+4], g5 = sgw[it*8+5], g6 = sgw[it*8+6], g7 = sgw[it*8+7];
            acc += g0*v0 + g1*v1 + g2*v2 + g3*v3 + g4*v4 + g5*v5 + g6*v6 + g7*v7;
        }
        sacc[quad][lane*4+0] = acc.x; sacc[quad][lane*4+1] = acc.y;
        sacc[quad][lane*4+2] = acc.z; sacc[quad][lane*4+3] = acc.w;
        __syncthreads();
        part[(size_t)(1+j)*256 + t] = sacc[0][t] + sacc[1][t] + sacc[2][t] + sacc[3][t];
    }
}

// ---- kernel 2: reduce part[4097][256] -> part2[64][256], skipping masked ----
__global__ __launch_bounds__(256) void k_red(const int* __restrict__ Xm,
                                             float* __restrict__ ws)
{
    int r = blockIdx.x, t = threadIdx.x;
    float acc = 0.f;
    for (int j = r; j < NPART; j += 64) {
        if (j == 0 || Xm[(j-1) >> 1] != 0) acc += ws[PART_OFF + (size_t)j*256 + t];
    }
    ws[PART2_OFF + r*256 + t] = acc;
}

// ---- kernel 3: end stack + final combine (1 block x 1024) ----
__global__ __launch_bounds__(1024) void k_end(
    const float* __restrict__ bef, const float* __restrict__ Wer,
    const float* __restrict__ ber, const float* __restrict__ Weo,
    const float* __restrict__ beo, const float* __restrict__ lw,
    float* __restrict__ out, float* __restrict__ ws)
{
    __shared__ float sx[256];
    __shared__ float racc[4][256];
    __shared__ float red0[1024], red1[1024];
    __shared__ float endraw[4][2];
    int tid = threadIdx.x;
    int q = tid >> 8, t = tid & 255;

    float acc = 0.f;
    #pragma unroll
    for (int j = 0; j < 16; ++j) acc += ws[PART2_OFF + (q*16 + j)*256 + t];
    racc[q][t] = acc;
    __syncthreads();
    float gsum = ws[GSUM_OFF];
    if (tid < 256) {
        float v = racc[0][t] + racc[1][t] + racc[2][t] + racc[3][t];
        sx[t] = fmaxf(v / gsum + bef[t], 0.f);
    }
    __syncthreads();

    #define HEAD_G(W2, B2, SCALE, DEST)                                         \
    {                                                                           \
        if (tid < 256) { red0[tid] = sx[tid]*(W2)[2*tid]; red1[tid] = sx[tid]*(W2)[2*tid+1]; } \
        __syncthreads();                                                        \
        for (int s = 128; s > 0; s >>= 1) {                                     \
            if (tid < s) { red0[tid] += red0[tid+s]; red1[tid] += red1[tid+s]; }\
            __syncthreads();                                                    \
        }                                                                       \
        if (tid == 0) {                                                         \
            float o0 = red0[0] + (B2)[0], o1 = red1[0] + (B2)[1];               \
            float m  = fmaxf(o0, o1);                                           \
            float e0 = expf(o0 - m), e1 = expf(o1 - m);                         \
            float inv = (SCALE) / (e0 + e1);                                    \
            (DEST)[0] = e0 * inv; (DEST)[1] = e1 * inv;                         \
        }                                                                       \
        __syncthreads();                                                        \
    }

    HEAD_G(Weo, beo, lw[2052], &endraw[0][0]);
    for (int i = 0; i < 3; ++i) {
        const float* Wq = Wer + i*65536 + (q*64)*256;
        float a2 = 0.f;
        #pragma unroll 16
        for (int k = 0; k < 64; ++k) a2 += sx[q*64 + k] * Wq[k*256 + t];
        racc[q][t] = a2;
        __syncthreads();
        if (tid < 256) {
            float v = racc[0][t] + racc[1][t] + racc[2][t] + racc[3][t];
            sx[t] = fmaxf(v + ber[i*256 + t], 0.f);
        }
        __syncthreads();
        HEAD_G(Weo + (i+1)*512, beo + (i+1)*2, lw[2053 + i], &endraw[i+1][0]);
    }

    float invw = 1.f / ws[WSUM_OFF];
    float s0 = 0.f, s1 = 0.f;
    for (int i = tid; i < NLAYERS; i += 1024) {
        float v0, v1;
        if (i >= 2052 && i < 2056) { v0 = endraw[i-2052][0]; v1 = endraw[i-2052][1]; }
        else                        { v0 = out[2 + 2*i];      v1 = out[2 + 2*i + 1]; }
        v0 *= invw; v1 *= invw;
        out[2 + 2*i]     = v0;
        out[2 + 2*i + 1] = v1;
        s0 += v0; s1 += v1;
    }
    red0[tid] = s0; red1[tid] = s1; __syncthreads();
    for (int s = 512; s > 0; s >>= 1) {
        if (tid < s) { red0[tid] += red0[tid+s]; red1[tid] += red1[tid+s]; }
        __syncthreads();
    }
    if (tid == 0) { out[0] = red0[0]; out[1] = red1[0]; }
}

extern "C" void kernel_launch(void* const* d_in, const int* in_sizes, int n_in,
                              void* d_out, int out_size, void* d_ws, size_t ws_size,
                              hipStream_t stream)
{
    const float* X    = (const float*)d_in[0];
    const int*   Xm   = (const int*)  d_in[1];
    const float* bfv  = (const float*)d_in[2];
    const float* Wbf  = (const float*)d_in[3];
    const float* bbf  = (const float*)d_in[4];
    const float* Wbr  = (const float*)d_in[5];
    const float* bbr  = (const float*)d_in[6];
    const float* Wbo  = (const float*)d_in[7];
    const float* bbo  = (const float*)d_in[8];
    const float* Wm   = (const float*)d_in[9];
    const float* bm   = (const float*)d_in[10];
    const float* Wmo  = (const float*)d_in[11];
    const float* bmo  = (const float*)d_in[12];
    const float* Wa   = (const float*)d_in[13];
    const float* ba   = (const float*)d_in[14];
    const float* Wao  = (const float*)d_in[15];
    const float* bao  = (const float*)d_in[16];
    const float* Wef  = (const float*)d_in[17];
    const float* bef  = (const float*)d_in[18];
    const float* Wer  = (const float*)d_in[19];
    const float* ber  = (const float*)d_in[20];
    const float* Weo  = (const float*)d_in[21];
    const float* beo  = (const float*)d_in[22];
    const float* lw   = (const float*)d_in[23];
    float* out = (float*)d_out;
    float* wsf = (float*)d_ws;

    hipMemsetAsync((char*)d_ws + (size_t)CTR_OFF * sizeof(float), 0, 4, stream);
    k_main<<<2048, 256, 0, stream>>>(X, Xm, bfv, Wbf, bbf, Wbr, bbr, Wbo, bbo,
                                     Wm, bm, Wmo, bmo, Wa, ba, Wao, bao,
                                     Wef, lw, Wer, Weo, bef, ber, out, wsf);
    k_red<<<64, 256, 0, stream>>>(Xm, wsf);
    k_end<<<1, 1024, 0, stream>>>(bef, Wer, ber, Weo, beo, lw, out, wsf);
}

// Round 8
// 106.527 us; speedup vs baseline: 1.4363x; 1.4363x over previous
//
#include <hip/hip_runtime.h>
#include <math.h>

#define A_N 2048
#define NLAYERS 2057
#define NCH 2049                  // part row 0 = middle, 1..nact = compacted experts

// ws layout (float/int offsets; 4B units so float and int offsets coincide)
#define PART_OFF  0               // 2049*256 = 524544
#define PART2_OFF 524544          // 64*256 = 16384
#define GSUM_OFF  540928
#define WSUM_OFF  540929
#define NACTI_OFF 540930          // int: number of active experts
#define LISTI_OFF 540932          // int[2048]: active experts first, then inactive

typedef float f4 __attribute__((ext_vector_type(4)));

// ---- helpers (256-thread sections) ----

__device__ __forceinline__ void head256(const float* sx, float* r0, float* r1,
                                        const float* W2, const float* b2,
                                        float scale, float* dest, int t)
{
    float xv = sx[t];
    r0[t] = xv * W2[2*t];
    r1[t] = xv * W2[2*t+1];
    __syncthreads();
    for (int s = 128; s > 0; s >>= 1) {
        if (t < s) { r0[t] += r0[t+s]; r1[t] += r1[t+s]; }
        __syncthreads();
    }
    if (t == 0) {
        float o0 = r0[0] + b2[0], o1 = r1[0] + b2[1];
        float m  = fmaxf(o0, o1);
        float e0 = expf(o0 - m), e1 = expf(o1 - m);
        float inv = scale / (e0 + e1);
        dest[0] = e0 * inv;
        dest[1] = e1 * inv;
    }
    __syncthreads();
}

// sx = relu(sx @ W + b), register-light (block-0 chain only)
__device__ __forceinline__ void mv256(float* sx, const float* __restrict__ W,
                                      const float* __restrict__ b, int t)
{
    float acc = 0.f;
    #pragma unroll 16
    for (int k = 0; k < 256; ++k) acc += sx[k] * W[k*256 + t];
    acc = fmaxf(acc + b[t], 0.f);
    __syncthreads();
    sx[t] = acc;
    __syncthreads();
}

// pull nf4 float4s at base into L3 (loads kept live via asm consume)
__device__ __forceinline__ void warm64k(const float* base, int nf4, int t)
{
    const f4* p = (const f4*)base;
    for (int i = t; i < nf4; i += 256) {
        f4 v = p[i];
        asm volatile("" :: "v"(v.x), "v"(v.y), "v"(v.z), "v"(v.w));
    }
}

// ---- kernel 0: compact active experts (1 block x 1024) ----
__global__ __launch_bounds__(1024) void k_list(const int* __restrict__ Xm,
                                               float* __restrict__ ws)
{
    __shared__ int scan[1024];
    int t = threadIdx.x;
    int a0 = (Xm[2*t]   != 0) ? 1 : 0;
    int a1 = (Xm[2*t+1] != 0) ? 1 : 0;
    int s = a0 + a1;
    scan[t] = s;
    __syncthreads();
    for (int off = 1; off < 1024; off <<= 1) {
        int v = (t >= off) ? scan[t-off] : 0;
        __syncthreads();
        scan[t] += v;
        __syncthreads();
    }
    int total = scan[1023];
    int excl  = scan[t] - s;           // actives before element 2t
    int* list = (int*)ws + LISTI_OFF;
    if (a0) list[excl] = 2*t;
    else    list[total + (2*t - excl)] = 2*t;
    if (a1) list[excl + a0] = 2*t + 1;
    else    list[total + (2*t + 1 - excl - a0)] = 2*t + 1;
    if (t == 0) ((int*)ws)[NACTI_OFF] = total;
}

// ---- kernel 1: base/middle chain + compacted expert chunks (2049 blocks) ----
// block 0: sums + base stack + middle + middle chunk of We_first
// block 1+idx: idx<nact -> expert list[idx]; else zero-out for expert list[idx]
__global__ __launch_bounds__(256) void k_main(
    const float* __restrict__ X, const int* __restrict__ Xm,
    const float* __restrict__ bfv,
    const float* __restrict__ Wbf, const float* __restrict__ bbf,
    const float* __restrict__ Wbr, const float* __restrict__ bbr,
    const float* __restrict__ Wbo, const float* __restrict__ bbo,
    const float* __restrict__ Wm, const float* __restrict__ bm,
    const float* __restrict__ Wmo, const float* __restrict__ bmo,
    const float* __restrict__ Wa, const float* __restrict__ ba,
    const float* __restrict__ Wao, const float* __restrict__ bao,
    const float* __restrict__ Wef, const float* __restrict__ lw,
    const float* __restrict__ Wer, const float* __restrict__ Weo,
    const float* __restrict__ bef, const float* __restrict__ ber,
    float* __restrict__ out, float* __restrict__ ws)
{
    __shared__ float sg[256];
    __shared__ float sacc[4][256];
    int b = blockIdx.x, t = threadIdx.x;
    int quad = t >> 6, lane = t & 63;
    float* part = ws + PART_OFF;

    // ---- L3 warming (blocks 1..34), then fall through to normal work ----
    if (b >= 1 && b <= 34) {
        int wi = b - 1;
        if      (wi < 12) warm64k(Wbr + (size_t)wi * 16384, 4096, t);        // 768KB
        else if (wi < 16) warm64k(Wm + (size_t)(wi - 12) * 16384, 4096, t);  // 256KB
        else if (wi < 28) warm64k(Wer + (size_t)(wi - 16) * 16384, 4096, t); // 768KB
        else if (wi == 28) { warm64k(Weo, 512, t); warm64k(Wbo, 512, t); }
        else if (wi == 29) { warm64k(Wmo, 128, t); warm64k(bef, 64, t); warm64k(ber, 192, t); }
        else warm64k(Wef + (size_t)A_N * 65536 + (size_t)(wi - 30) * 16384, 4096, t);
    }

    size_t rowbase;
    if (b == 0) {
        // ---- mask-weighted sums ----
        float ga = 0.f;
        for (int a = t; a < A_N; a += 256) if (Xm[a] != 0) ga += lw[4 + a];
        sacc[0][t] = ga; __syncthreads();
        for (int s = 128; s > 0; s >>= 1) { if (t < s) sacc[0][t] += sacc[0][t+s]; __syncthreads(); }
        if (t == 0) {
            float gaux = sacc[0][0];
            ws[GSUM_OFF] = gaux + lw[2056];
            ws[WSUM_OFF] = lw[0]+lw[1]+lw[2]+lw[3] + gaux
                         + lw[2052]+lw[2053]+lw[2054]+lw[2055]+lw[2056];
        }
        __syncthreads();

        // ---- base stack + middle ----
        sg[t] = fmaxf(bfv[0] * Wbf[t] + bbf[t], 0.f);
        __syncthreads();
        head256(sg, sacc[0], sacc[1], Wbo, bbo, lw[0], out + 2, t);
        for (int i = 0; i < 3; ++i) {
            mv256(sg, Wbr + i*65536, bbr + i*256, t);
            head256(sg, sacc[0], sacc[1], Wbo + (i+1)*512, bbo + (i+1)*2,
                    lw[i+1], out + 2 + (i+1)*2, t);
        }
        mv256(sg, Wm, bm, t);
        head256(sg, sacc[0], sacc[1], Wmo, bmo, lw[2056], out + 2 + 2056*2, t);
        sg[t] *= lw[2056];
        __syncthreads();
        rowbase = (size_t)A_N * 65536;
    } else {
        int idx  = b - 1;
        int nact = ((const int*)ws)[NACTI_OFF];
        const int* list = (const int*)ws + LISTI_OFF;
        int e = list[idx];
        if (idx >= nact) {                 // inactive expert: just zero its out row
            if (t == 0) { out[2 + (4+e)*2] = 0.f; out[2 + (4+e)*2 + 1] = 0.f; }
            return;
        }
        float xv = X[e];
        float w  = lw[4 + e];
        float h  = fmaxf(xv * Wa[e*256 + t] + ba[e*256 + t], 0.f);
        float2 wo = *(const float2*)&Wao[(size_t)e*512 + 2*t];
        sacc[0][t] = h * wo.x;
        sacc[1][t] = h * wo.y;
        sg[t] = h * w;                     // u = h*mask*lw (mask==1 here)
        __syncthreads();
        for (int s = 128; s > 0; s >>= 1) {
            if (t < s) { sacc[0][t] += sacc[0][t+s]; sacc[1][t] += sacc[1][t+s]; }
            __syncthreads();
        }
        if (t == 0) {
            float o0 = sacc[0][0] + bao[2*e], o1 = sacc[1][0] + bao[2*e+1];
            float m  = fmaxf(o0, o1);
            float e0 = expf(o0 - m), e1 = expf(o1 - m);
            float inv = w / (e0 + e1);     // * lw * mask; /wsum deferred
            out[2 + (4+e)*2]     = e0 * inv;
            out[2 + (4+e)*2 + 1] = e1 * inv;
        }
        __syncthreads();
        rowbase = (size_t)e * 65536;
    }

    // ---- partial matvec: 256 rows of We_first for this chunk ----
    // wave `quad` owns rows [quad*64, quad*64+64); lane owns cols [4*lane, 4*lane+4).
    // 8 independent float4 loads batched per iteration -> 128 B/thread in flight.
    const f4* Wb4 = (const f4*)(Wef + rowbase) + (size_t)quad*64*64 + lane;
    const float* sgw = sg + quad*64;
    f4 acc = {0.f, 0.f, 0.f, 0.f};
    #pragma unroll
    for (int it = 0; it < 8; ++it) {
        f4 v0 = Wb4[(it*8+0)*64]; f4 v1 = Wb4[(it*8+1)*64];
        f4 v2 = Wb4[(it*8+2)*64]; f4 v3 = Wb4[(it*8+3)*64];
        f4 v4 = Wb4[(it*8+4)*64]; f4 v5 = Wb4[(it*8+5)*64];
        f4 v6 = Wb4[(it*8+6)*64]; f4 v7 = Wb4[(it*8+7)*64];
        float g0 = sgw[it*8+0], g1 = sgw[it*8+1], g2 = sgw[it*8+2], g3 = sgw[it*8+3];
        float g4 = sgw[it*8+4], g5 = sgw[it*8+5], g6 = sgw[it*8+6], g7 = sgw[it*8+7];
        acc += g0*v0 + g1*v1 + g2*v2 + g3*v3 + g4*v4 + g5*v5 + g6*v6 + g7*v7;
    }
    sacc[quad][lane*4+0] = acc.x; sacc[quad][lane*4+1] = acc.y;
    sacc[quad][lane*4+2] = acc.z; sacc[quad][lane*4+3] = acc.w;
    __syncthreads();
    part[(size_t)b*256 + t] = sacc[0][t] + sacc[1][t] + sacc[2][t] + sacc[3][t];
}

// ---- kernel 2: reduce part rows 0..nact -> part2[64][256] ----
__global__ __launch_bounds__(256) void k_red(float* __restrict__ ws)
{
    int r = blockIdx.x, t = threadIdx.x;
    int nact = ((const int*)ws)[NACTI_OFF];
    float acc = 0.f;
    for (int j = r; j <= nact; j += 64) {
        acc += ws[PART_OFF + (size_t)j*256 + t];
    }
    ws[PART2_OFF + r*256 + t] = acc;
}

// ---- kernel 3: end stack + final combine (1 block x 1024) ----
__global__ __launch_bounds__(1024) void k_end(
    const float* __restrict__ bef, const float* __restrict__ Wer,
    const float* __restrict__ ber, const float* __restrict__ Weo,
    const float* __restrict__ beo, const float* __restrict__ lw,
    float* __restrict__ out, float* __restrict__ ws)
{
    __shared__ float sx[256];
    __shared__ float racc[4][256];
    __shared__ float red0[1024], red1[1024];
    __shared__ float endraw[4][2];
    int tid = threadIdx.x;
    int q = tid >> 8, t = tid & 255;

    float acc = 0.f;
    #pragma unroll
    for (int j = 0; j < 16; ++j) acc += ws[PART2_OFF + (q*16 + j)*256 + t];
    racc[q][t] = acc;
    __syncthreads();
    float gsum = ws[GSUM_OFF];
    if (tid < 256) {
        float v = racc[0][t] + racc[1][t] + racc[2][t] + racc[3][t];
        sx[t] = fmaxf(v / gsum + bef[t], 0.f);
    }
    __syncthreads();

    #define HEAD_G(W2, B2, SCALE, DEST)                                         \
    {                                                                           \
        if (tid < 256) { red0[tid] = sx[tid]*(W2)[2*tid]; red1[tid] = sx[tid]*(W2)[2*tid+1]; } \
        __syncthreads();                                                        \
        for (int s = 128; s > 0; s >>= 1) {                                     \
            if (tid < s) { red0[tid] += red0[tid+s]; red1[tid] += red1[tid+s]; }\
            __syncthreads();                                                    \
        }                                                                       \
        if (tid == 0) {                                                         \
            float o0 = red0[0] + (B2)[0], o1 = red1[0] + (B2)[1];               \
            float m  = fmaxf(o0, o1);                                           \
            float e0 = expf(o0 - m), e1 = expf(o1 - m);                         \
            float inv = (SCALE) / (e0 + e1);                                    \
            (DEST)[0] = e0 * inv; (DEST)[1] = e1 * inv;                         \
        }                                                                       \
        __syncthreads();                                                        \
    }

    HEAD_G(Weo, beo, lw[2052], &endraw[0][0]);
    for (int i = 0; i < 3; ++i) {
        const float* Wq = Wer + i*65536 + (q*64)*256;
        float a2 = 0.f;
        #pragma unroll 16
        for (int k = 0; k < 64; ++k) a2 += sx[q*64 + k] * Wq[k*256 + t];
        racc[q][t] = a2;
        __syncthreads();
        if (tid < 256) {
            float v = racc[0][t] + racc[1][t] + racc[2][t] + racc[3][t];
            sx[t] = fmaxf(v + ber[i*256 + t], 0.f);
        }
        __syncthreads();
        HEAD_G(Weo + (i+1)*512, beo + (i+1)*2, lw[2053 + i], &endraw[i+1][0]);
    }

    float invw = 1.f / ws[WSUM_OFF];
    float s0 = 0.f, s1 = 0.f;
    for (int i = tid; i < NLAYERS; i += 1024) {
        float v0, v1;
        if (i >= 2052 && i < 2056) { v0 = endraw[i-2052][0]; v1 = endraw[i-2052][1]; }
        else                        { v0 = out[2 + 2*i];      v1 = out[2 + 2*i + 1]; }
        v0 *= invw; v1 *= invw;
        out[2 + 2*i]     = v0;
        out[2 + 2*i + 1] = v1;
        s0 += v0; s1 += v1;
    }
    red0[tid] = s0; red1[tid] = s1; __syncthreads();
    for (int s = 512; s > 0; s >>= 1) {
        if (tid < s) { red0[tid] += red0[tid+s]; red1[tid] += red1[tid+s]; }
        __syncthreads();
    }
    if (tid == 0) { out[0] = red0[0]; out[1] = red1[0]; }
}

extern "C" void kernel_launch(void* const* d_in, const int* in_sizes, int n_in,
                              void* d_out, int out_size, void* d_ws, size_t ws_size,
                              hipStream_t stream)
{
    const float* X    = (const float*)d_in[0];
    const int*   Xm   = (const int*)  d_in[1];
    const float* bfv  = (const float*)d_in[2];
    const float* Wbf  = (const float*)d_in[3];
    const float* bbf  = (const float*)d_in[4];
    const float* Wbr  = (const float*)d_in[5];
    const float* bbr  = (const float*)d_in[6];
    const float* Wbo  = (const float*)d_in[7];
    const float* bbo  = (const float*)d_in[8];
    const float* Wm   = (const float*)d_in[9];
    const float* bm   = (const float*)d_in[10];
    const float* Wmo  = (const float*)d_in[11];
    const float* bmo  = (const float*)d_in[12];
    const float* Wa   = (const float*)d_in[13];
    const float* ba   = (const float*)d_in[14];
    const float* Wao  = (const float*)d_in[15];
    const float* bao  = (const float*)d_in[16];
    const float* Wef  = (const float*)d_in[17];
    const float* bef  = (const float*)d_in[18];
    const float* Wer  = (const float*)d_in[19];
    const float* ber  = (const float*)d_in[20];
    const float* Weo  = (const float*)d_in[21];
    const float* beo  = (const float*)d_in[22];
    const float* lw   = (const float*)d_in[23];
    float* out = (float*)d_out;
    float* wsf = (float*)d_ws;

    k_list<<<1, 1024, 0, stream>>>(Xm, wsf);
    k_main<<<NCH, 256, 0, stream>>>(X, Xm, bfv, Wbf, bbf, Wbr, bbr, Wbo, bbo,
                                    Wm, bm, Wmo, bmo, Wa, ba, Wao, bao,
                                    Wef, lw, Wer, Weo, bef, ber, out, wsf);
    k_red<<<64, 256, 0, stream>>>(wsf);
    k_end<<<1, 1024, 0, stream>>>(bef, Wer, ber, Weo, beo, lw, out, wsf);
}

// Round 9
// 102.280 us; speedup vs baseline: 1.4960x; 1.0415x over previous
//
#include <hip/hip_runtime.h>
#include <math.h>

#define A_N 2048
#define NLAYERS 2057
#define NCH 2049                  // grid: block 0 = middle/chain, 1..2048 = compacted slots

// ws layout (4B units; float and int offsets coincide)
#define PART_OFF  0               // 2049*256 = 524544
#define PART2_OFF 524544          // 64*256 = 16384
#define GSUM_OFF  540928
#define WSUM_OFF  540929
#define NACTI_OFF 540930          // int: number of active experts
#define LISTI_OFF 540932          // int[2048]: compacted active expert ids

typedef float f4 __attribute__((ext_vector_type(4)));

// ---- helpers (256-thread sections) ----

__device__ __forceinline__ void head256(const float* sx, float* r0, float* r1,
                                        const float* W2, const float* b2,
                                        float scale, float* dest, int t)
{
    float xv = sx[t];
    r0[t] = xv * W2[2*t];
    r1[t] = xv * W2[2*t+1];
    __syncthreads();
    for (int s = 128; s > 0; s >>= 1) {
        if (t < s) { r0[t] += r0[t+s]; r1[t] += r1[t+s]; }
        __syncthreads();
    }
    if (t == 0) {
        float o0 = r0[0] + b2[0], o1 = r1[0] + b2[1];
        float m  = fmaxf(o0, o1);
        float e0 = expf(o0 - m), e1 = expf(o1 - m);
        float inv = scale / (e0 + e1);
        dest[0] = e0 * inv;
        dest[1] = e1 * inv;
    }
    __syncthreads();
}

// sx = relu(sx @ W + b), register-light (block-0 chain only)
__device__ __forceinline__ void mv256(float* sx, const float* __restrict__ W,
                                      const float* __restrict__ b, int t)
{
    float acc = 0.f;
    #pragma unroll 16
    for (int k = 0; k < 256; ++k) acc += sx[k] * W[k*256 + t];
    acc = fmaxf(acc + b[t], 0.f);
    __syncthreads();
    sx[t] = acc;
    __syncthreads();
}

// pull nf4 float4s at base into L3 (loads kept live via asm consume)
__device__ __forceinline__ void warm64k(const float* base, int nf4, int t)
{
    const f4* p = (const f4*)base;
    for (int i = t; i < nf4; i += 256) {
        f4 v = p[i];
        asm volatile("" :: "v"(v.x), "v"(v.y), "v"(v.z), "v"(v.w));
    }
}

// ---- kernel 0: compaction + sums + inactive-row zeroing (1 block x 1024) ----
__global__ __launch_bounds__(1024) void k_list(const int* __restrict__ Xm,
                                               const float* __restrict__ lw,
                                               float* __restrict__ out,
                                               float* __restrict__ ws)
{
    __shared__ int scan[1024];
    __shared__ float fred[1024];
    int t = threadIdx.x;
    int e0 = 2*t, e1 = 2*t + 1;
    int a0 = (Xm[e0] != 0) ? 1 : 0;
    int a1 = (Xm[e1] != 0) ? 1 : 0;
    int s = a0 + a1;
    scan[t] = s;
    fred[t] = (a0 ? lw[4+e0] : 0.f) + (a1 ? lw[4+e1] : 0.f);
    __syncthreads();
    for (int off = 1; off < 1024; off <<= 1) {
        int v = (t >= off) ? scan[t-off] : 0;
        __syncthreads();
        scan[t] += v;
        __syncthreads();
    }
    for (int ss = 512; ss > 0; ss >>= 1) {
        if (t < ss) fred[t] += fred[t+ss];
        __syncthreads();
    }
    int total = scan[1023];
    int excl  = scan[t] - s;           // actives before element e0
    int* list = (int*)ws + LISTI_OFF;
    if (a0) list[excl] = e0;
    else    { out[2 + (4+e0)*2] = 0.f; out[2 + (4+e0)*2 + 1] = 0.f; }
    if (a1) list[excl + a0] = e1;
    else    { out[2 + (4+e1)*2] = 0.f; out[2 + (4+e1)*2 + 1] = 0.f; }
    if (t == 0) {
        ((int*)ws)[NACTI_OFF] = total;
        float gaux = fred[0];
        ws[GSUM_OFF] = gaux + lw[2056];
        ws[WSUM_OFF] = lw[0]+lw[1]+lw[2]+lw[3] + gaux
                     + lw[2052]+lw[2053]+lw[2054]+lw[2055]+lw[2056];
    }
}

// ---- kernel 1: chain (block 0) + compacted expert chunks (2049 blocks) ----
// __launch_bounds__(256, 8): cap VGPR at 64 -> 8 blocks/CU resident.
__global__ __launch_bounds__(256, 8) void k_main(
    const float* __restrict__ X,
    const float* __restrict__ bfv,
    const float* __restrict__ Wbf, const float* __restrict__ bbf,
    const float* __restrict__ Wbr, const float* __restrict__ bbr,
    const float* __restrict__ Wbo, const float* __restrict__ bbo,
    const float* __restrict__ Wm, const float* __restrict__ bm,
    const float* __restrict__ Wmo, const float* __restrict__ bmo,
    const float* __restrict__ Wa, const float* __restrict__ ba,
    const float* __restrict__ Wao, const float* __restrict__ bao,
    const float* __restrict__ Wef, const float* __restrict__ lw,
    const float* __restrict__ Wer, const float* __restrict__ Weo,
    const float* __restrict__ bef, const float* __restrict__ ber,
    float* __restrict__ out, float* __restrict__ ws)
{
    __shared__ float sg[256];
    __shared__ float sacc[4][256];
    int b = blockIdx.x, t = threadIdx.x;
    int quad = t >> 6, lane = t & 63;
    float* part = ws + PART_OFF;

    size_t rowbase;
    if (b == 0) {
        // ---- base stack + middle (serial chain; weights L3-warmed by blocks 1..34) ----
        sg[t] = fmaxf(bfv[0] * Wbf[t] + bbf[t], 0.f);
        __syncthreads();
        head256(sg, sacc[0], sacc[1], Wbo, bbo, lw[0], out + 2, t);
        for (int i = 0; i < 3; ++i) {
            mv256(sg, Wbr + i*65536, bbr + i*256, t);
            head256(sg, sacc[0], sacc[1], Wbo + (i+1)*512, bbo + (i+1)*2,
                    lw[i+1], out + 2 + (i+1)*2, t);
        }
        mv256(sg, Wm, bm, t);
        head256(sg, sacc[0], sacc[1], Wmo, bmo, lw[2056], out + 2 + 2056*2, t);
        sg[t] *= lw[2056];
        __syncthreads();
        rowbase = (size_t)A_N * 65536;
    } else {
        int idx  = b - 1;
        int nact = ((const int*)ws)[NACTI_OFF];
        if (idx >= nact) return;           // instant exit (k_list zeroed out rows)

        // ---- L3 warming for chain + end-stack weights (blocks 1..34) ----
        if (b <= 34) {
            int wi = b - 1;
            if      (wi < 12) warm64k(Wbr + (size_t)wi * 16384, 4096, t);        // 768KB
            else if (wi < 16) warm64k(Wm + (size_t)(wi - 12) * 16384, 4096, t);  // 256KB
            else if (wi < 28) warm64k(Wer + (size_t)(wi - 16) * 16384, 4096, t); // 768KB
            else if (wi == 28) { warm64k(Weo, 512, t); warm64k(Wbo, 512, t); }
            else if (wi == 29) { warm64k(Wmo, 128, t); warm64k(bef, 64, t); warm64k(ber, 192, t); }
            else warm64k(Wef + (size_t)A_N * 65536 + (size_t)(wi - 30) * 16384, 4096, t);
        }

        int e = ((const int*)ws + LISTI_OFF)[idx];
        float xv = X[e];
        float w  = lw[4 + e];
        float h  = fmaxf(xv * Wa[e*256 + t] + ba[e*256 + t], 0.f);
        float2 wo = *(const float2*)&Wao[(size_t)e*512 + 2*t];
        sacc[0][t] = h * wo.x;
        sacc[1][t] = h * wo.y;
        sg[t] = h * w;                     // u = h*mask*lw (mask==1 here)
        __syncthreads();
        for (int s = 128; s > 0; s >>= 1) {
            if (t < s) { sacc[0][t] += sacc[0][t+s]; sacc[1][t] += sacc[1][t+s]; }
            __syncthreads();
        }
        if (t == 0) {
            float o0 = sacc[0][0] + bao[2*e], o1 = sacc[1][0] + bao[2*e+1];
            float m  = fmaxf(o0, o1);
            float e0 = expf(o0 - m), e1 = expf(o1 - m);
            float inv = w / (e0 + e1);     // * lw * mask; /wsum deferred
            out[2 + (4+e)*2]     = e0 * inv;
            out[2 + (4+e)*2 + 1] = e1 * inv;
        }
        __syncthreads();
        rowbase = (size_t)e * 65536;
    }

    // ---- partial matvec: 256 rows of We_first for this chunk ----
    // wave `quad` owns rows [quad*64, quad*64+64); lane owns cols [4*lane, 4*lane+4).
    // 8 independent float4 loads batched per iteration -> 128 B/thread in flight.
    const f4* Wb4 = (const f4*)(Wef + rowbase) + (size_t)quad*64*64 + lane;
    const float* sgw = sg + quad*64;
    f4 acc = {0.f, 0.f, 0.f, 0.f};
    #pragma unroll
    for (int it = 0; it < 8; ++it) {
        f4 v0 = Wb4[(it*8+0)*64]; f4 v1 = Wb4[(it*8+1)*64];
        f4 v2 = Wb4[(it*8+2)*64]; f4 v3 = Wb4[(it*8+3)*64];
        f4 v4 = Wb4[(it*8+4)*64]; f4 v5 = Wb4[(it*8+5)*64];
        f4 v6 = Wb4[(it*8+6)*64]; f4 v7 = Wb4[(it*8+7)*64];
        float g0 = sgw[it*8+0], g1 = sgw[it*8+1], g2 = sgw[it*8+2], g3 = sgw[it*8+3];
        float g4 = sgw[it*8+4], g5 = sgw[it*8+5], g6 = sgw[it*8+6], g7 = sgw[it*8+7];
        acc += g0*v0 + g1*v1 + g2*v2 + g3*v3 + g4*v4 + g5*v5 + g6*v6 + g7*v7;
    }
    sacc[quad][lane*4+0] = acc.x; sacc[quad][lane*4+1] = acc.y;
    sacc[quad][lane*4+2] = acc.z; sacc[quad][lane*4+3] = acc.w;
    __syncthreads();
    part[(size_t)b*256 + t] = sacc[0][t] + sacc[1][t] + sacc[2][t] + sacc[3][t];
}

// ---- kernel 2: reduce part rows 0..nact -> part2[64][256] ----
__global__ __launch_bounds__(256) void k_red(float* __restrict__ ws)
{
    int r = blockIdx.x, t = threadIdx.x;
    int nact = ((const int*)ws)[NACTI_OFF];
    float acc = 0.f;
    for (int j = r; j <= nact; j += 64) {
        acc += ws[PART_OFF + (size_t)j*256 + t];
    }
    ws[PART2_OFF + r*256 + t] = acc;
}

// ---- kernel 3: end stack + final combine (1 block x 1024) ----
__global__ __launch_bounds__(1024) void k_end(
    const float* __restrict__ bef, const float* __restrict__ Wer,
    const float* __restrict__ ber, const float* __restrict__ Weo,
    const float* __restrict__ beo, const float* __restrict__ lw,
    float* __restrict__ out, float* __restrict__ ws)
{
    __shared__ float sx[256];
    __shared__ float racc[4][256];
    __shared__ float red0[1024], red1[1024];
    __shared__ float endraw[4][2];
    int tid = threadIdx.x;
    int q = tid >> 8, t = tid & 255;

    float acc = 0.f;
    #pragma unroll
    for (int j = 0; j < 16; ++j) acc += ws[PART2_OFF + (q*16 + j)*256 + t];
    racc[q][t] = acc;
    __syncthreads();
    float gsum = ws[GSUM_OFF];
    if (tid < 256) {
        float v = racc[0][t] + racc[1][t] + racc[2][t] + racc[3][t];
        sx[t] = fmaxf(v / gsum + bef[t], 0.f);
    }
    __syncthreads();

    #define HEAD_G(W2, B2, SCALE, DEST)                                         \
    {                                                                           \
        if (tid < 256) { red0[tid] = sx[tid]*(W2)[2*tid]; red1[tid] = sx[tid]*(W2)[2*tid+1]; } \
        __syncthreads();                                                        \
        for (int s = 128; s > 0; s >>= 1) {                                     \
            if (tid < s) { red0[tid] += red0[tid+s]; red1[tid] += red1[tid+s]; }\
            __syncthreads();                                                    \
        }                                                                       \
        if (tid == 0) {                                                         \
            float o0 = red0[0] + (B2)[0], o1 = red1[0] + (B2)[1];               \
            float m  = fmaxf(o0, o1);                                           \
            float e0 = expf(o0 - m), e1 = expf(o1 - m);                         \
            float inv = (SCALE) / (e0 + e1);                                    \
            (DEST)[0] = e0 * inv; (DEST)[1] = e1 * inv;                         \
        }                                                                       \
        __syncthreads();                                                        \
    }

    HEAD_G(Weo, beo, lw[2052], &endraw[0][0]);
    for (int i = 0; i < 3; ++i) {
        const float* Wq = Wer + i*65536 + (q*64)*256;
        float a2 = 0.f;
        #pragma unroll 16
        for (int k = 0; k < 64; ++k) a2 += sx[q*64 + k] * Wq[k*256 + t];
        racc[q][t] = a2;
        __syncthreads();
        if (tid < 256) {
            float v = racc[0][t] + racc[1][t] + racc[2][t] + racc[3][t];
            sx[t] = fmaxf(v + ber[i*256 + t], 0.f);
        }
        __syncthreads();
        HEAD_G(Weo + (i+1)*512, beo + (i+1)*2, lw[2053 + i], &endraw[i+1][0]);
    }

    float invw = 1.f / ws[WSUM_OFF];
    float s0 = 0.f, s1 = 0.f;
    for (int i = tid; i < NLAYERS; i += 1024) {
        float v0, v1;
        if (i >= 2052 && i < 2056) { v0 = endraw[i-2052][0]; v1 = endraw[i-2052][1]; }
        else                        { v0 = out[2 + 2*i];      v1 = out[2 + 2*i + 1]; }
        v0 *= invw; v1 *= invw;
        out[2 + 2*i]     = v0;
        out[2 + 2*i + 1] = v1;
        s0 += v0; s1 += v1;
    }
    red0[tid] = s0; red1[tid] = s1; __syncthreads();
    for (int s = 512; s > 0; s >>= 1) {
        if (tid < s) { red0[tid] += red0[tid+s]; red1[tid] += red1[tid+s]; }
        __syncthreads();
    }
    if (tid == 0) { out[0] = red0[0]; out[1] = red1[0]; }
}

extern "C" void kernel_launch(void* const* d_in, const int* in_sizes, int n_in,
                              void* d_out, int out_size, void* d_ws, size_t ws_size,
                              hipStream_t stream)
{
    const float* X    = (const float*)d_in[0];
    const int*   Xm   = (const int*)  d_in[1];
    const float* bfv  = (const float*)d_in[2];
    const float* Wbf  = (const float*)d_in[3];
    const float* bbf  = (const float*)d_in[4];
    const float* Wbr  = (const float*)d_in[5];
    const float* bbr  = (const float*)d_in[6];
    const float* Wbo  = (const float*)d_in[7];
    const float* bbo  = (const float*)d_in[8];
    const float* Wm   = (const float*)d_in[9];
    const float* bm   = (const float*)d_in[10];
    const float* Wmo  = (const float*)d_in[11];
    const float* bmo  = (const float*)d_in[12];
    const float* Wa   = (const float*)d_in[13];
    const float* ba   = (const float*)d_in[14];
    const float* Wao  = (const float*)d_in[15];
    const float* bao  = (const float*)d_in[16];
    const float* Wef  = (const float*)d_in[17];
    const float* bef  = (const float*)d_in[18];
    const float* Wer  = (const float*)d_in[19];
    const float* ber  = (const float*)d_in[20];
    const float* Weo  = (const float*)d_in[21];
    const float* beo  = (const float*)d_in[22];
    const float* lw   = (const float*)d_in[23];
    float* out = (float*)d_out;
    float* wsf = (float*)d_ws;

    k_list<<<1, 1024, 0, stream>>>(Xm, lw, out, wsf);
    k_main<<<NCH, 256, 0, stream>>>(X, bfv, Wbf, bbf, Wbr, bbr, Wbo, bbo,
                                    Wm, bm, Wmo, bmo, Wa, ba, Wao, bao,
                                    Wef, lw, Wer, Weo, bef, ber, out, wsf);
    k_red<<<64, 256, 0, stream>>>(wsf);
    k_end<<<1, 1024, 0, stream>>>(bef, Wer, ber, Weo, beo, lw, out, wsf);
}

// Round 10
// 85.484 us; speedup vs baseline: 1.7899x; 1.1965x over previous
//
#include <hip/hip_runtime.h>
#include <math.h>

#define A_N 2048
#define NLAYERS 2057
#define NCH 2049                  // grid: block 0 = middle/chain, 1..2048 = compacted slots

// ws layout (4B units; float and int offsets coincide)
#define PART_OFF  0               // 2049*256 = 524544
#define PART2_OFF 524544          // 64*256 = 16384
#define GSUM_OFF  540928
#define WSUM_OFF  540929
#define NACTI_OFF 540930          // int: number of active experts
#define LISTI_OFF 540932          // int[2048]: compacted active expert ids

typedef float f4 __attribute__((ext_vector_type(4)));

// ---- helpers (256-thread sections) ----

__device__ __forceinline__ void head256(const float* sx, float* r0, float* r1,
                                        const float* W2, const float* b2,
                                        float scale, float* dest, int t)
{
    float xv = sx[t];
    r0[t] = xv * W2[2*t];
    r1[t] = xv * W2[2*t+1];
    __syncthreads();
    for (int s = 128; s > 0; s >>= 1) {
        if (t < s) { r0[t] += r0[t+s]; r1[t] += r1[t+s]; }
        __syncthreads();
    }
    if (t == 0) {
        float o0 = r0[0] + b2[0], o1 = r1[0] + b2[1];
        float m  = fmaxf(o0, o1);
        float e0 = expf(o0 - m), e1 = expf(o1 - m);
        float inv = scale / (e0 + e1);
        dest[0] = e0 * inv;
        dest[1] = e1 * inv;
    }
    __syncthreads();
}

// sx = relu(sx @ W + b), register-light (block-0 chain only)
__device__ __forceinline__ void mv256(float* sx, const float* __restrict__ W,
                                      const float* __restrict__ b, int t)
{
    float acc = 0.f;
    #pragma unroll 16
    for (int k = 0; k < 256; ++k) acc += sx[k] * W[k*256 + t];
    acc = fmaxf(acc + b[t], 0.f);
    __syncthreads();
    sx[t] = acc;
    __syncthreads();
}

// pull nf4 float4s at base into cache (loads kept live via asm consume)
__device__ __forceinline__ void warm64k(const float* base, int nf4, int t)
{
    const f4* p = (const f4*)base;
    for (int i = t; i < nf4; i += 256) {
        f4 v = p[i];
        asm volatile("" :: "v"(v.x), "v"(v.y), "v"(v.z), "v"(v.w));
    }
}

// ---- kernel 0: compaction + sums + inactive-row zeroing (1 block x 1024) ----
__global__ __launch_bounds__(1024) void k_list(const int* __restrict__ Xm,
                                               const float* __restrict__ lw,
                                               float* __restrict__ out,
                                               float* __restrict__ ws)
{
    __shared__ int scan[1024];
    __shared__ float fred[1024];
    int t = threadIdx.x;
    int e0 = 2*t, e1 = 2*t + 1;
    int a0 = (Xm[e0] != 0) ? 1 : 0;
    int a1 = (Xm[e1] != 0) ? 1 : 0;
    int s = a0 + a1;
    scan[t] = s;
    fred[t] = (a0 ? lw[4+e0] : 0.f) + (a1 ? lw[4+e1] : 0.f);
    __syncthreads();
    for (int off = 1; off < 1024; off <<= 1) {
        int v = (t >= off) ? scan[t-off] : 0;
        __syncthreads();
        scan[t] += v;
        __syncthreads();
    }
    for (int ss = 512; ss > 0; ss >>= 1) {
        if (t < ss) fred[t] += fred[t+ss];
        __syncthreads();
    }
    int total = scan[1023];
    int excl  = scan[t] - s;           // actives before element e0
    int* list = (int*)ws + LISTI_OFF;
    if (a0) list[excl] = e0;
    else    { out[2 + (4+e0)*2] = 0.f; out[2 + (4+e0)*2 + 1] = 0.f; }
    if (a1) list[excl + a0] = e1;
    else    { out[2 + (4+e1)*2] = 0.f; out[2 + (4+e1)*2 + 1] = 0.f; }
    if (t == 0) {
        ((int*)ws)[NACTI_OFF] = total;
        float gaux = fred[0];
        ws[GSUM_OFF] = gaux + lw[2056];
        ws[WSUM_OFF] = lw[0]+lw[1]+lw[2]+lw[3] + gaux
                     + lw[2052]+lw[2053]+lw[2054]+lw[2055]+lw[2056];
    }
}

// ---- kernel 1: chain (block 0) + compacted expert chunks, ReLU-row-gated ----
__global__ __launch_bounds__(256, 4) void k_main(
    const float* __restrict__ X,
    const float* __restrict__ bfv,
    const float* __restrict__ Wbf, const float* __restrict__ bbf,
    const float* __restrict__ Wbr, const float* __restrict__ bbr,
    const float* __restrict__ Wbo, const float* __restrict__ bbo,
    const float* __restrict__ Wm, const float* __restrict__ bm,
    const float* __restrict__ Wmo, const float* __restrict__ bmo,
    const float* __restrict__ Wa, const float* __restrict__ ba,
    const float* __restrict__ Wao, const float* __restrict__ bao,
    const float* __restrict__ Wef, const float* __restrict__ lw,
    float* __restrict__ out, float* __restrict__ ws)
{
    __shared__ float sg[256];
    __shared__ float sacc[4][256];
    __shared__ float gl[288];
    __shared__ int   rlist[288];
    __shared__ int   swcnt[4];
    int b = blockIdx.x, t = threadIdx.x;
    int quad = t >> 6, lane = t & 63;
    float* part = ws + PART_OFF;

    float val;                          // this thread's row coefficient (row = t)
    size_t rowbase;
    if (b == 0) {
        // ---- base stack + middle (weights warmed by blocks 1..21) ----
        sg[t] = fmaxf(bfv[0] * Wbf[t] + bbf[t], 0.f);
        __syncthreads();
        head256(sg, sacc[0], sacc[1], Wbo, bbo, lw[0], out + 2, t);
        for (int i = 0; i < 3; ++i) {
            mv256(sg, Wbr + i*65536, bbr + i*256, t);
            head256(sg, sacc[0], sacc[1], Wbo + (i+1)*512, bbo + (i+1)*2,
                    lw[i+1], out + 2 + (i+1)*2, t);
        }
        mv256(sg, Wm, bm, t);
        head256(sg, sacc[0], sacc[1], Wmo, bmo, lw[2056], out + 2 + 2056*2, t);
        val = sg[t] * lw[2056];
        rowbase = (size_t)A_N * 65536;
    } else {
        int idx  = b - 1;
        int nact = ((const int*)ws)[NACTI_OFF];
        if (idx >= nact) return;        // instant exit (k_list zeroed out rows)

        // ---- L3 warming for the serial chain (blocks 1..21) ----
        if (b <= 21) {
            int wi = b - 1;
            if      (wi < 12) warm64k(Wbr + (size_t)wi * 16384, 4096, t);        // 768KB
            else if (wi < 16) warm64k(Wm + (size_t)(wi - 12) * 16384, 4096, t);  // 256KB
            else if (wi == 16) { warm64k(Wbo, 512, t); warm64k(Wmo, 128, t); }
            else warm64k(Wef + (size_t)A_N * 65536 + (size_t)(wi - 17) * 16384, 4096, t); // mid chunk, wi 17..20
        }

        int e = ((const int*)ws + LISTI_OFF)[idx];
        float xv = X[e];
        float w  = lw[4 + e];
        float h  = fmaxf(xv * Wa[e*256 + t] + ba[e*256 + t], 0.f);
        float2 wo = *(const float2*)&Wao[(size_t)e*512 + 2*t];
        sacc[0][t] = h * wo.x;
        sacc[1][t] = h * wo.y;
        __syncthreads();
        for (int s = 128; s > 0; s >>= 1) {
            if (t < s) { sacc[0][t] += sacc[0][t+s]; sacc[1][t] += sacc[1][t+s]; }
            __syncthreads();
        }
        if (t == 0) {
            float o0 = sacc[0][0] + bao[2*e], o1 = sacc[1][0] + bao[2*e+1];
            float m  = fmaxf(o0, o1);
            float e0 = expf(o0 - m), e1 = expf(o1 - m);
            float inv = w / (e0 + e1);  // * lw * mask; /wsum deferred
            out[2 + (4+e)*2]     = e0 * inv;
            out[2 + (4+e)*2 + 1] = e1 * inv;
        }
        val = h * w;
        rowbase = (size_t)e * 65536;
    }

    // ---- compact nonzero rows (exact: rows with val==0 contribute nothing) ----
    bool pred = (val != 0.f);
    unsigned long long m = __ballot(pred);
    if (lane == 0) swcnt[quad] = (int)__popcll(m);
    __syncthreads();
    int nr = swcnt[0] + swcnt[1] + swcnt[2] + swcnt[3];
    int offs = 0;
    #pragma unroll
    for (int q2 = 0; q2 < 4; ++q2) if (q2 < quad) offs += swcnt[q2];
    int rank = (int)__popcll(m & ((1ull << lane) - 1ull));
    if (pred) { int pos = offs + rank; rlist[pos] = t; gl[pos] = val; }
    if (t < 32) { rlist[nr + t] = 0; gl[nr + t] = 0.f; }   // padded tail (g=0)
    __syncthreads();

    // ---- gated partial matvec over compacted rows (8-batched 1KB row reads) ----
    const f4* Wb4c = (const f4*)(Wef + rowbase) + lane;
    f4 acc = {0.f, 0.f, 0.f, 0.f};
    int niter = (nr + 31) >> 5;         // 32 rows/iter (8 per wave)
    for (int it = 0; it < niter; ++it) {
        int base = it*32 + quad*8;
        int r0 = rlist[base+0], r1 = rlist[base+1], r2 = rlist[base+2], r3 = rlist[base+3];
        int r4 = rlist[base+4], r5 = rlist[base+5], r6 = rlist[base+6], r7 = rlist[base+7];
        float g0 = gl[base+0], g1 = gl[base+1], g2 = gl[base+2], g3 = gl[base+3];
        float g4 = gl[base+4], g5 = gl[base+5], g6 = gl[base+6], g7 = gl[base+7];
        f4 v0 = Wb4c[(size_t)r0*64]; f4 v1 = Wb4c[(size_t)r1*64];
        f4 v2 = Wb4c[(size_t)r2*64]; f4 v3 = Wb4c[(size_t)r3*64];
        f4 v4 = Wb4c[(size_t)r4*64]; f4 v5 = Wb4c[(size_t)r5*64];
        f4 v6 = Wb4c[(size_t)r6*64]; f4 v7 = Wb4c[(size_t)r7*64];
        acc += g0*v0 + g1*v1 + g2*v2 + g3*v3 + g4*v4 + g5*v5 + g6*v6 + g7*v7;
    }
    sacc[quad][lane*4+0] = acc.x; sacc[quad][lane*4+1] = acc.y;
    sacc[quad][lane*4+2] = acc.z; sacc[quad][lane*4+3] = acc.w;
    __syncthreads();
    part[(size_t)b*256 + t] = sacc[0][t] + sacc[1][t] + sacc[2][t] + sacc[3][t];
}

// ---- kernel 2: reduce part rows 0..nact -> part2[64][256]; warm end weights ----
__global__ __launch_bounds__(256) void k_red(
    const float* __restrict__ Wer, const float* __restrict__ Weo,
    const float* __restrict__ bef, const float* __restrict__ ber,
    const float* __restrict__ beo, float* __restrict__ ws)
{
    int r = blockIdx.x, t = threadIdx.x;
    // re-warm end-stack weights (evicted by the 268MB Wef stream) for k_end
    if (r < 48) warm64k(Wer + (size_t)r * 4096, 1024, t);        // 16KB each = 768KB
    else if (r == 48) {
        warm64k(Weo, 512, t); warm64k(bef, 64, t);
        warm64k(ber, 192, t); warm64k(beo, 2, t);
    }
    int nact = ((const int*)ws)[NACTI_OFF];
    float acc = 0.f;
    for (int j = r; j <= nact; j += 64) {
        acc += ws[PART_OFF + (size_t)j*256 + t];
    }
    ws[PART2_OFF + r*256 + t] = acc;
}

// ---- kernel 3: end stack + final combine (1 block x 1024) ----
__global__ __launch_bounds__(1024) void k_end(
    const float* __restrict__ bef, const float* __restrict__ Wer,
    const float* __restrict__ ber, const float* __restrict__ Weo,
    const float* __restrict__ beo, const float* __restrict__ lw,
    float* __restrict__ out, float* __restrict__ ws)
{
    __shared__ float sx[256];
    __shared__ float racc[4][256];
    __shared__ float red0[1024], red1[1024];
    __shared__ float endraw[4][2];
    int tid = threadIdx.x;
    int q = tid >> 8, t = tid & 255;

    float acc = 0.f;
    #pragma unroll
    for (int j = 0; j < 16; ++j) acc += ws[PART2_OFF + (q*16 + j)*256 + t];
    racc[q][t] = acc;
    __syncthreads();
    float gsum = ws[GSUM_OFF];
    if (tid < 256) {
        float v = racc[0][t] + racc[1][t] + racc[2][t] + racc[3][t];
        sx[t] = fmaxf(v / gsum + bef[t], 0.f);
    }
    __syncthreads();

    #define HEAD_G(W2, B2, SCALE, DEST)                                         \
    {                                                                           \
        if (tid < 256) { red0[tid] = sx[tid]*(W2)[2*tid]; red1[tid] = sx[tid]*(W2)[2*tid+1]; } \
        __syncthreads();                                                        \
        for (int s = 128; s > 0; s >>= 1) {                                     \
            if (tid < s) { red0[tid] += red0[tid+s]; red1[tid] += red1[tid+s]; }\
            __syncthreads();                                                    \
        }                                                                       \
        if (tid == 0) {                                                         \
            float o0 = red0[0] + (B2)[0], o1 = red1[0] + (B2)[1];               \
            float m  = fmaxf(o0, o1);                                           \
            float e0 = expf(o0 - m), e1 = expf(o1 - m);                         \
            float inv = (SCALE) / (e0 + e1);                                    \
            (DEST)[0] = e0 * inv; (DEST)[1] = e1 * inv;                         \
        }                                                                       \
        __syncthreads();                                                        \
    }

    HEAD_G(Weo, beo, lw[2052], &endraw[0][0]);
    for (int i = 0; i < 3; ++i) {
        const float* Wq = Wer + i*65536 + (q*64)*256;
        float a2 = 0.f;
        #pragma unroll 16
        for (int k = 0; k < 64; ++k) a2 += sx[q*64 + k] * Wq[k*256 + t];
        racc[q][t] = a2;
        __syncthreads();
        if (tid < 256) {
            float v = racc[0][t] + racc[1][t] + racc[2][t] + racc[3][t];
            sx[t] = fmaxf(v + ber[i*256 + t], 0.f);
        }
        __syncthreads();
        HEAD_G(Weo + (i+1)*512, beo + (i+1)*2, lw[2053 + i], &endraw[i+1][0]);
    }

    float invw = 1.f / ws[WSUM_OFF];
    float s0 = 0.f, s1 = 0.f;
    for (int i = tid; i < NLAYERS; i += 1024) {
        float v0, v1;
        if (i >= 2052 && i < 2056) { v0 = endraw[i-2052][0]; v1 = endraw[i-2052][1]; }
        else                        { v0 = out[2 + 2*i];      v1 = out[2 + 2*i + 1]; }
        v0 *= invw; v1 *= invw;
        out[2 + 2*i]     = v0;
        out[2 + 2*i + 1] = v1;
        s0 += v0; s1 += v1;
    }
    red0[tid] = s0; red1[tid] = s1; __syncthreads();
    for (int s = 512; s > 0; s >>= 1) {
        if (tid < s) { red0[tid] += red0[tid+s]; red1[tid] += red1[tid+s]; }
        __syncthreads();
    }
    if (tid == 0) { out[0] = red0[0]; out[1] = red1[0]; }
}

extern "C" void kernel_launch(void* const* d_in, const int* in_sizes, int n_in,
                              void* d_out, int out_size, void* d_ws, size_t ws_size,
                              hipStream_t stream)
{
    const float* X    = (const float*)d_in[0];
    const int*   Xm   = (const int*)  d_in[1];
    const float* bfv  = (const float*)d_in[2];
    const float* Wbf  = (const float*)d_in[3];
    const float* bbf  = (const float*)d_in[4];
    const float* Wbr  = (const float*)d_in[5];
    const float* bbr  = (const float*)d_in[6];
    const float* Wbo  = (const float*)d_in[7];
    const float* bbo  = (const float*)d_in[8];
    const float* Wm   = (const float*)d_in[9];
    const float* bm   = (const float*)d_in[10];
    const float* Wmo  = (const float*)d_in[11];
    const float* bmo  = (const float*)d_in[12];
    const float* Wa   = (const float*)d_in[13];
    const float* ba   = (const float*)d_in[14];
    const float* Wao  = (const float*)d_in[15];
    const float* bao  = (const float*)d_in[16];
    const float* Wef  = (const float*)d_in[17];
    const float* bef  = (const float*)d_in[18];
    const float* Wer  = (const float*)d_in[19];
    const float* ber  = (const float*)d_in[20];
    const float* Weo  = (const float*)d_in[21];
    const float* beo  = (const float*)d_in[22];
    const float* lw   = (const float*)d_in[23];
    float* out = (float*)d_out;
    float* wsf = (float*)d_ws;

    k_list<<<1, 1024, 0, stream>>>(Xm, lw, out, wsf);
    k_main<<<NCH, 256, 0, stream>>>(X, bfv, Wbf, bbf, Wbr, bbr, Wbo, bbo,
                                    Wm, bm, Wmo, bmo, Wa, ba, Wao, bao,
                                    Wef, lw, out, wsf);
    k_red<<<64, 256, 0, stream>>>(Wer, Weo, bef, ber, beo, wsf);
    k_end<<<1, 1024, 0, stream>>>(bef, Wer, ber, Weo, beo, lw, out, wsf);
}